// Round 1
// baseline (5244.030 us; speedup 1.0000x reference)
//
#include <hip/hip_runtime.h>

// WindowAttention (Swin-style), MI355X fp32 baseline.
// DIM=384, WIN=7, N=49, HEADS=12, hd=32, NUM_WINDOWS=64, B_W=2048.
// Round 0: correctness-first fp32. Kernel 1 fuses qkv+attention per window;
// kernel 2 does the output projection in-place on d_out (no workspace needed).
// Future rounds: bf16 MFMA for qkv/proj GEMMs once absmax margin is known.

#define DIMC   384
#define NTOK   49
#define NHEAD  12
#define HD     32
#define NWIN   64
#define BWIN   2048
#define SCALE  0.17677669529663687f  // 1/sqrt(32)

__device__ __forceinline__ float4 ld4(const float* p) {
    return *reinterpret_cast<const float4*>(p);
}

// ---------------------------------------------------------------------------
// Kernel 1: per-window fused qkv + attention. Block = 192 threads (3 waves).
// Thread map for GEMM phase: tx = t%12 (8 cols each -> 96 cols = q|k|v of one
// head), ty = t/12 (4 rows each -> 64 >= 49 rows).
// LDS: xs_t (x chunk, transposed, stride 68 so float4 row reads stay in
// bounds & 16B aligned), u.w (weight chunk) aliased with u.s (scores).
// ---------------------------------------------------------------------------
__global__ __launch_bounds__(192) void k_qkv_attn(
    const float* __restrict__ x,          // (2048,49,384)
    const float* __restrict__ mask,       // (64,49,49)
    const float* __restrict__ qkv_w,      // (384,1152)
    const float* __restrict__ qkv_b,      // (1152)
    const float* __restrict__ bias_table, // (169,12)
    const int*   __restrict__ rel_idx,    // (49,49)
    float* __restrict__ out)              // (2048,49,384) pre-proj
{
    __shared__ __align__(16) float xs_t[64 * 68];            // 17.4 KB
    __shared__ __align__(16) float qs[NTOK * HD];            // 6.3 KB
    __shared__ __align__(16) float ks_[NTOK * HD];           // 6.3 KB
    __shared__ __align__(16) float vs[NTOK * HD];            // 6.3 KB
    __shared__ __align__(16) union {
        float w[64 * 96];   // weight chunk (24.6 KB)
        float s[NTOK * 56]; // scores, row stride 56 (10.8 KB)
    } u;

    const int t  = threadIdx.x;
    const int b  = blockIdx.x;
    const int tx = t % 12;          // col group: c = tx*8 .. tx*8+7
    const int ty = t / 12;          // row group: i = ty*4 .. ty*4+3
    const float* xb = x + (size_t)b * NTOK * DIMC;
    const int mbase = (b % NWIN) * NTOK * NTOK;

    for (int h = 0; h < NHEAD; ++h) {
        float acc[4][8];
        #pragma unroll
        for (int r = 0; r < 4; ++r)
            #pragma unroll
            for (int cc = 0; cc < 8; ++cc) acc[r][cc] = 0.0f;

        // ---- qkv GEMM for head h: (49x384) @ (384x96) ----
        for (int c0 = 0; c0 < DIMC; c0 += 64) {
            // stage x chunk transposed: xs_t[kk*68 + i] = x[b][i][c0+kk]
            for (int idx = t; idx < NTOK * 64; idx += 192) {
                int i = idx >> 6, kk = idx & 63;
                xs_t[kk * 68 + i] = xb[i * DIMC + c0 + kk];
            }
            // stage weight chunk: cols 0..31 -> q, 32..63 -> k, 64..95 -> v
            for (int idx = t; idx < 64 * 96; idx += 192) {
                int kk = idx / 96, c = idx % 96;
                int col = (c >> 5) * DIMC + h * HD + (c & 31);
                u.w[kk * 96 + c] = qkv_w[(size_t)(c0 + kk) * (3 * DIMC) + col];
            }
            __syncthreads();
            #pragma unroll 8
            for (int kk = 0; kk < 64; ++kk) {
                const float4 xv = ld4(&xs_t[kk * 68 + ty * 4]);
                const float4 w0 = ld4(&u.w[kk * 96 + tx * 8]);
                const float4 w1 = ld4(&u.w[kk * 96 + tx * 8 + 4]);
                const float xr[4] = {xv.x, xv.y, xv.z, xv.w};
                const float wc[8] = {w0.x, w0.y, w0.z, w0.w,
                                     w1.x, w1.y, w1.z, w1.w};
                #pragma unroll
                for (int r = 0; r < 4; ++r)
                    #pragma unroll
                    for (int cc = 0; cc < 8; ++cc)
                        acc[r][cc] = fmaf(xr[r], wc[cc], acc[r][cc]);
            }
            __syncthreads();
        }

        // ---- scatter q,k,v into LDS (each thread's 8 cols are one part) ----
        {
            const int part  = tx >> 2;            // 0=q, 1=k, 2=v
            const int cbase = (tx & 3) * 8;       // offset within head dim
            float* dst = (part == 0) ? qs : (part == 1) ? ks_ : vs;
            #pragma unroll
            for (int r = 0; r < 4; ++r) {
                int i = ty * 4 + r;
                if (i < NTOK) {
                    #pragma unroll
                    for (int cc = 0; cc < 8; ++cc) {
                        int c5  = cbase + cc;
                        int col = part * DIMC + h * HD + c5;
                        dst[i * HD + c5] = acc[r][cc] + qkv_b[col];
                    }
                }
            }
        }
        __syncthreads();

        // ---- scores: s[i][j] = scale*q_i.k_j + bias[h][i][j] + mask[b%64][i][j]
        for (int o = t; o < NTOK * NTOK; o += 192) {
            int i = o / 49, j = o % 49;
            float4 a4 = {0.f, 0.f, 0.f, 0.f};
            #pragma unroll
            for (int seg = 0; seg < 8; ++seg) {
                float4 q4 = ld4(&qs[i * HD + seg * 4]);
                float4 k4 = ld4(&ks_[j * HD + seg * 4]);
                a4.x = fmaf(q4.x, k4.x, a4.x);
                a4.y = fmaf(q4.y, k4.y, a4.y);
                a4.z = fmaf(q4.z, k4.z, a4.z);
                a4.w = fmaf(q4.w, k4.w, a4.w);
            }
            float s = (a4.x + a4.y + a4.z + a4.w) * SCALE
                    + bias_table[rel_idx[o] * NHEAD + h]
                    + mask[mbase + o];
            u.s[i * 56 + j] = s;
        }
        __syncthreads();

        // ---- softmax per row (49 rows, one thread each) ----
        if (t < NTOK) {
            float* row = &u.s[t * 56];
            float m = row[0];
            for (int j = 1; j < NTOK; ++j) m = fmaxf(m, row[j]);
            float ssum = 0.f;
            for (int j = 0; j < NTOK; ++j) {
                float e = __expf(row[j] - m);
                row[j] = e;
                ssum += e;
            }
            float inv = 1.0f / ssum;
            for (int j = 0; j < NTOK; ++j) row[j] *= inv;
        }
        __syncthreads();

        // ---- out_head = P @ V, write pre-proj to d_out ----
        for (int o = t; o < NTOK * 8; o += 192) {
            int i = o >> 3, dg = o & 7;
            float4 a = {0.f, 0.f, 0.f, 0.f};
            for (int j = 0; j < NTOK; ++j) {
                float sj  = u.s[i * 56 + j];
                float4 v4 = ld4(&vs[j * HD + dg * 4]);
                a.x = fmaf(sj, v4.x, a.x);
                a.y = fmaf(sj, v4.y, a.y);
                a.z = fmaf(sj, v4.z, a.z);
                a.w = fmaf(sj, v4.w, a.w);
            }
            *reinterpret_cast<float4*>(
                &out[(size_t)(b * NTOK + i) * DIMC + h * HD + dg * 4]) = a;
        }
        __syncthreads();  // before next head reuses u.w / qs / ks / vs
    }
}

// ---------------------------------------------------------------------------
// Kernel 2: in-place output projection. Block = 192 threads, 16 rows/block.
// All 16 rows are staged into LDS BEFORE any global write, so in-place on
// d_out is safe (blocks own disjoint rows; kernels serialize on the stream).
// Thread map: tx = t%48 (8 cols each -> 384), ty = t/48 (4 rows each -> 16).
// ---------------------------------------------------------------------------
__global__ __launch_bounds__(192) void k_proj(
    float* __restrict__ io,            // (100352, 384), read then overwritten
    const float* __restrict__ proj_w,  // (384,384)
    const float* __restrict__ proj_b)  // (384)
{
    __shared__ __align__(16) float ys_t[DIMC * 20];  // 30.7 KB, stride 20
    __shared__ __align__(16) float wch[16 * DIMC];   // 24.6 KB

    const int t    = threadIdx.x;
    const int row0 = blockIdx.x * 16;
    const int tx   = t % 48;
    const int ty   = t / 48;

    // stage 16 rows, transposed: ys_t[k*20 + i] = io[row0+i][k]
    for (int idx = t; idx < 16 * DIMC; idx += 192) {
        int i = idx / DIMC, k = idx % DIMC;
        ys_t[k * 20 + i] = io[(size_t)(row0 + i) * DIMC + k];
    }

    float acc[4][8];
    #pragma unroll
    for (int r = 0; r < 4; ++r)
        #pragma unroll
        for (int cc = 0; cc < 8; ++cc) acc[r][cc] = 0.0f;

    for (int k0 = 0; k0 < DIMC; k0 += 16) {
        for (int idx = t; idx < 16 * DIMC; idx += 192) {
            int kk = idx / DIMC, c = idx % DIMC;
            wch[kk * DIMC + c] = proj_w[(size_t)(k0 + kk) * DIMC + c];
        }
        __syncthreads();
        #pragma unroll
        for (int kk = 0; kk < 16; ++kk) {
            const float4 xv = ld4(&ys_t[(k0 + kk) * 20 + ty * 4]);
            const float4 w0 = ld4(&wch[kk * DIMC + tx * 8]);
            const float4 w1 = ld4(&wch[kk * DIMC + tx * 8 + 4]);
            const float xr[4] = {xv.x, xv.y, xv.z, xv.w};
            const float wc[8] = {w0.x, w0.y, w0.z, w0.w,
                                 w1.x, w1.y, w1.z, w1.w};
            #pragma unroll
            for (int r = 0; r < 4; ++r)
                #pragma unroll
                for (int cc = 0; cc < 8; ++cc)
                    acc[r][cc] = fmaf(xr[r], wc[cc], acc[r][cc]);
        }
        __syncthreads();
    }

    // epilogue: + bias, write back (rows already fully consumed into LDS)
    #pragma unroll
    for (int r = 0; r < 4; ++r) {
        int i = ty * 4 + r;
        float4 o0, o1;
        o0.x = acc[r][0] + proj_b[tx * 8 + 0];
        o0.y = acc[r][1] + proj_b[tx * 8 + 1];
        o0.z = acc[r][2] + proj_b[tx * 8 + 2];
        o0.w = acc[r][3] + proj_b[tx * 8 + 3];
        o1.x = acc[r][4] + proj_b[tx * 8 + 4];
        o1.y = acc[r][5] + proj_b[tx * 8 + 5];
        o1.z = acc[r][6] + proj_b[tx * 8 + 6];
        o1.w = acc[r][7] + proj_b[tx * 8 + 7];
        float* dst = &io[(size_t)(row0 + i) * DIMC + tx * 8];
        *reinterpret_cast<float4*>(dst)     = o0;
        *reinterpret_cast<float4*>(dst + 4) = o1;
    }
}

extern "C" void kernel_launch(void* const* d_in, const int* in_sizes, int n_in,
                              void* d_out, int out_size, void* d_ws, size_t ws_size,
                              hipStream_t stream) {
    const float* x          = (const float*)d_in[0];
    const float* mask       = (const float*)d_in[1];
    const float* qkv_w      = (const float*)d_in[2];
    const float* qkv_b      = (const float*)d_in[3];
    const float* proj_w     = (const float*)d_in[4];
    const float* proj_b     = (const float*)d_in[5];
    const float* bias_table = (const float*)d_in[6];
    const int*   rel_idx    = (const int*)d_in[7];
    float* out = (float*)d_out;

    k_qkv_attn<<<BWIN, 192, 0, stream>>>(x, mask, qkv_w, qkv_b,
                                         bias_table, rel_idx, out);
    k_proj<<<(BWIN * NTOK) / 16, 192, 0, stream>>>(out, proj_w, proj_b);
}

// Round 4
// 1861.038 us; speedup vs baseline: 2.8178x; 2.8178x over previous
//
#include <hip/hip_runtime.h>

// WindowAttention (Swin-style), MI355X. Round 4: MFMA GEMMs + scalar attention.
// Round-3 bug fixed: K1/K3 B-tile staging loops only covered 1024/4096 LDS
// elements (scalar writes with a stride meant for x4 vector writes) ->
// uninitialized LDS -> garbage/NaN. Now fully covered + vectorized.
// K1: qkv GEMM (split-bf16 3-term MFMA) -> ws slots [b*12+h][{q,k,v}][49][32] bf16
// K2: per-(b,h) scalar/VALU attention (P kept fp32), bf16 out -> own q slot
// K3: proj GEMM (A bf16, W split 2-term MFMA) -> d_out fp32
// Fallback: round-0 fp32 kernels if ws_size < 231 MB.

#define DIMC   384
#define NTOK   49
#define NHEAD  12
#define HD     32
#define NWIN   64
#define BWIN   2048
#define SCALE  0.17677669529663687f  // 1/sqrt(32)

#define SLOT   4704        // ushorts per (b,h): 3*49*32
#define WS_NEED ((size_t)BWIN * NHEAD * SLOT * 2)   // 231,211,008 bytes

typedef short bf16x8 __attribute__((ext_vector_type(8)));
typedef float f32x4  __attribute__((ext_vector_type(4)));

__device__ __forceinline__ unsigned short f2bf(float f) {
    union { float f; unsigned u; } v; v.f = f;
    unsigned r = v.u + 0x7fffu + ((v.u >> 16) & 1u);   // RTN-even
    return (unsigned short)(r >> 16);
}
__device__ __forceinline__ float bf2f(unsigned short h) {
    union { unsigned u; float f; } v; v.u = ((unsigned)h) << 16;
    return v.f;
}
__device__ __forceinline__ void split2(float x, unsigned short& hi, unsigned short& lo) {
    hi = f2bf(x);
    lo = f2bf(x - bf2f(hi));
}
__device__ __forceinline__ float4 ld4(const float* p) {
    return *reinterpret_cast<const float4*>(p);
}

// ---------------------------------------------------------------------------
// K1: Y = X(100352x384) @ W(384x1152) + b, split-bf16, out bf16 to ws slots.
// Grid (784, 9), block 256 = 4 waves in 2x2. BM=BN=128, BK=32, LDS stride 40.
// ---------------------------------------------------------------------------
__global__ __launch_bounds__(256) void k_gemm_qkv(
    const float* __restrict__ x, const float* __restrict__ w,
    const float* __restrict__ qb, unsigned short* __restrict__ ws)
{
    __shared__ __align__(16) unsigned short Ah[128 * 40], Al[128 * 40];
    __shared__ __align__(16) unsigned short Bh[128 * 40], Bl[128 * 40];

    const int t = threadIdx.x;
    const int wave = t >> 6, l = t & 63, lj = l & 15, quad = l >> 4;
    const int wm = wave & 1, wn = wave >> 1;
    const int gm0 = blockIdx.x * 128, gn0 = blockIdx.y * 128;

    f32x4 acc[4][4];
    #pragma unroll
    for (int i = 0; i < 4; ++i)
        #pragma unroll
        for (int j = 0; j < 4; ++j) acc[i][j] = (f32x4)0.0f;

    for (int kc = 0; kc < 12; ++kc) {
        // stage A tile (128x32 fp32 -> hi/lo bf16); 4 elems/thread/iter
        #pragma unroll
        for (int it = 0; it < 4; ++it) {
            int idx = it * 1024 + t * 4;          // multiples of 4 in [0,4096)
            int m = idx >> 5, k = idx & 31;
            float4 xv = ld4(x + (size_t)(gm0 + m) * DIMC + kc * 32 + k);
            ushort4 h4, l4;
            split2(xv.x, h4.x, l4.x); split2(xv.y, h4.y, l4.y);
            split2(xv.z, h4.z, l4.z); split2(xv.w, h4.w, l4.w);
            *reinterpret_cast<ushort4*>(&Ah[m * 40 + k]) = h4;
            *reinterpret_cast<ushort4*>(&Al[m * 40 + k]) = l4;
        }
        // stage W tile transposed (32x128 -> Wt[n][k] hi/lo); FULL coverage:
        // float4 over n, 4 scattered bf16 writes (round-3 bug was 25% cover)
        #pragma unroll
        for (int g = 0; g < 4; ++g) {
            int idx = g * 1024 + t * 4;           // multiples of 4 in [0,4096)
            int n4 = idx & 127, k = idx >> 7;     // n4 in {0,4,..,124}, k in [0,32)
            float4 wv = ld4(w + (size_t)(kc * 32 + k) * (3 * DIMC) + gn0 + n4);
            unsigned short hh, ll;
            split2(wv.x, hh, ll); Bh[(n4 + 0) * 40 + k] = hh; Bl[(n4 + 0) * 40 + k] = ll;
            split2(wv.y, hh, ll); Bh[(n4 + 1) * 40 + k] = hh; Bl[(n4 + 1) * 40 + k] = ll;
            split2(wv.z, hh, ll); Bh[(n4 + 2) * 40 + k] = hh; Bl[(n4 + 2) * 40 + k] = ll;
            split2(wv.w, hh, ll); Bh[(n4 + 3) * 40 + k] = hh; Bl[(n4 + 3) * 40 + k] = ll;
        }
        __syncthreads();

        bf16x8 ah[4], alo[4], bh[4], blo[4];
        #pragma unroll
        for (int i = 0; i < 4; ++i) {
            int ra = (wm * 64 + i * 16 + lj) * 40 + quad * 8;
            ah[i]  = *reinterpret_cast<const bf16x8*>(&Ah[ra]);
            alo[i] = *reinterpret_cast<const bf16x8*>(&Al[ra]);
            int rb = (wn * 64 + i * 16 + lj) * 40 + quad * 8;
            bh[i]  = *reinterpret_cast<const bf16x8*>(&Bh[rb]);
            blo[i] = *reinterpret_cast<const bf16x8*>(&Bl[rb]);
        }
        #pragma unroll
        for (int tm = 0; tm < 4; ++tm)
            #pragma unroll
            for (int tn = 0; tn < 4; ++tn) {
                acc[tm][tn] = __builtin_amdgcn_mfma_f32_16x16x32_bf16(ah[tm],  bh[tn],  acc[tm][tn], 0, 0, 0);
                acc[tm][tn] = __builtin_amdgcn_mfma_f32_16x16x32_bf16(ah[tm],  blo[tn], acc[tm][tn], 0, 0, 0);
                acc[tm][tn] = __builtin_amdgcn_mfma_f32_16x16x32_bf16(alo[tm], bh[tn],  acc[tm][tn], 0, 0, 0);
            }
        __syncthreads();
    }

    // epilogue: +bias, bf16, scatter into (b,h,part) slots
    #pragma unroll
    for (int tn = 0; tn < 4; ++tn) {
        int col = gn0 + wn * 64 + tn * 16 + lj;          // 0..1151
        float bias = qb[col];
        int part = col / 384, rem = col - part * 384;
        int h = rem >> 5, d = rem & 31;
        #pragma unroll
        for (int tm = 0; tm < 4; ++tm) {
            #pragma unroll
            for (int rr = 0; rr < 4; ++rr) {
                int row = gm0 + wm * 64 + tm * 16 + quad * 4 + rr;
                int b = row / 49, n = row - b * 49;
                size_t off = ((size_t)(b * NHEAD + h) * 3 + part) * 1568 + n * HD + d;
                ws[off] = f2bf(acc[tm][tn][rr] + bias);
            }
        }
    }
}

// ---------------------------------------------------------------------------
// K2: scalar/VALU attention per (b,h). Block = 256. Stage q,k,v fp32 in LDS;
// scores + bias + mask; per-row softmax (P stays fp32); P@V; bf16 result
// overwrites own q slot.
// ---------------------------------------------------------------------------
__global__ __launch_bounds__(256) void k_attn_scalar(
    unsigned short* __restrict__ ws, const float* __restrict__ mask,
    const float* __restrict__ bias_table, const int* __restrict__ rel_idx)
{
    __shared__ float qf[NTOK * HD];     // 6.3 KB
    __shared__ float kf[NTOK * HD];     // 6.3 KB
    __shared__ float vf[NTOK * HD];     // 6.3 KB
    __shared__ float sf[NTOK * 52];     // 10.2 KB

    const int t = threadIdx.x, bx = blockIdx.x;    // bx = b*12 + h
    const int b = bx / NHEAD, h = bx - b * NHEAD;
    unsigned short* qp = ws + (size_t)bx * SLOT;

    for (int i = t; i < NTOK * HD; i += 256) {
        qf[i] = bf2f(qp[i]);
        kf[i] = bf2f(qp[1568 + i]);
        vf[i] = bf2f(qp[3136 + i]);
    }
    __syncthreads();

    const int mb = (b & (NWIN - 1)) * NTOK * NTOK;
    for (int o = t; o < NTOK * NTOK; o += 256) {
        int i = o / NTOK, j = o - i * NTOK;
        float a = 0.0f;
        #pragma unroll
        for (int d = 0; d < HD; ++d) a = fmaf(qf[i * HD + d], kf[j * HD + d], a);
        sf[i * 52 + j] = a * SCALE + bias_table[rel_idx[o] * NHEAD + h] + mask[mb + o];
    }
    __syncthreads();

    if (t < NTOK) {
        float* row = &sf[t * 52];
        float m = row[0];
        for (int j = 1; j < NTOK; ++j) m = fmaxf(m, row[j]);
        float s = 0.0f;
        for (int j = 0; j < NTOK; ++j) { float e = __expf(row[j] - m); row[j] = e; s += e; }
        float inv = 1.0f / s;
        for (int j = 0; j < NTOK; ++j) row[j] *= inv;
    }
    __syncthreads();

    for (int o = t; o < NTOK * HD; o += 256) {
        int i = o >> 5, d = o & 31;
        float a = 0.0f;
        for (int j = 0; j < NTOK; ++j) a = fmaf(sf[i * 52 + j], vf[j * HD + d], a);
        qp[o] = f2bf(a);   // global write; all global reads finished pre-barrier
    }
}

// ---------------------------------------------------------------------------
// K3: out = Y2(100352x384, bf16 in ws q-slots) @ proj_w(384x384) + b, fp32 out.
// Grid (784, 3), block 256. A plain bf16, W split 2-term. BK=32, kc == head.
// ---------------------------------------------------------------------------
__global__ __launch_bounds__(256) void k_gemm_proj(
    const unsigned short* __restrict__ ws, const float* __restrict__ w,
    const float* __restrict__ pbias, float* __restrict__ out)
{
    __shared__ __align__(16) unsigned short As[128 * 40];
    __shared__ __align__(16) unsigned short Bh[128 * 40], Bl[128 * 40];

    const int t = threadIdx.x;
    const int wave = t >> 6, l = t & 63, lj = l & 15, quad = l >> 4;
    const int wm = wave & 1, wn = wave >> 1;
    const int gm0 = blockIdx.x * 128, gn0 = blockIdx.y * 128;

    f32x4 acc[4][4];
    #pragma unroll
    for (int i = 0; i < 4; ++i)
        #pragma unroll
        for (int j = 0; j < 4; ++j) acc[i][j] = (f32x4)0.0f;

    for (int kc = 0; kc < 12; ++kc) {       // kc == head index
        // stage A from gathered slots (ushort4 per thread -> full coverage)
        #pragma unroll
        for (int it = 0; it < 4; ++it) {
            int e4 = it * 256 + t;
            int r = e4 >> 3, kq = e4 & 7;            // kq*4 = d offset
            int row = gm0 + r;
            int b = row / 49, n = row - b * 49;
            const unsigned short* src = ws + (size_t)(b * NHEAD + kc) * SLOT + n * HD + kq * 4;
            *reinterpret_cast<ushort4*>(&As[r * 40 + kq * 4]) =
                *reinterpret_cast<const ushort4*>(src);
        }
        // stage W transposed hi/lo; FULL coverage (float4 over n)
        #pragma unroll
        for (int g = 0; g < 4; ++g) {
            int idx = g * 1024 + t * 4;
            int n4 = idx & 127, k = idx >> 7;
            float4 wv = ld4(w + (size_t)(kc * 32 + k) * DIMC + gn0 + n4);
            unsigned short hh, ll;
            split2(wv.x, hh, ll); Bh[(n4 + 0) * 40 + k] = hh; Bl[(n4 + 0) * 40 + k] = ll;
            split2(wv.y, hh, ll); Bh[(n4 + 1) * 40 + k] = hh; Bl[(n4 + 1) * 40 + k] = ll;
            split2(wv.z, hh, ll); Bh[(n4 + 2) * 40 + k] = hh; Bl[(n4 + 2) * 40 + k] = ll;
            split2(wv.w, hh, ll); Bh[(n4 + 3) * 40 + k] = hh; Bl[(n4 + 3) * 40 + k] = ll;
        }
        __syncthreads();

        bf16x8 a[4], bh[4], blo[4];
        #pragma unroll
        for (int i = 0; i < 4; ++i) {
            a[i]   = *reinterpret_cast<const bf16x8*>(&As[(wm * 64 + i * 16 + lj) * 40 + quad * 8]);
            int rb = (wn * 64 + i * 16 + lj) * 40 + quad * 8;
            bh[i]  = *reinterpret_cast<const bf16x8*>(&Bh[rb]);
            blo[i] = *reinterpret_cast<const bf16x8*>(&Bl[rb]);
        }
        #pragma unroll
        for (int tm = 0; tm < 4; ++tm)
            #pragma unroll
            for (int tn = 0; tn < 4; ++tn) {
                acc[tm][tn] = __builtin_amdgcn_mfma_f32_16x16x32_bf16(a[tm], bh[tn],  acc[tm][tn], 0, 0, 0);
                acc[tm][tn] = __builtin_amdgcn_mfma_f32_16x16x32_bf16(a[tm], blo[tn], acc[tm][tn], 0, 0, 0);
            }
        __syncthreads();
    }

    #pragma unroll
    for (int tn = 0; tn < 4; ++tn) {
        int col = gn0 + wn * 64 + tn * 16 + lj;
        float bias = pbias[col];
        #pragma unroll
        for (int tm = 0; tm < 4; ++tm)
            #pragma unroll
            for (int rr = 0; rr < 4; ++rr) {
                int row = gm0 + wm * 64 + tm * 16 + quad * 4 + rr;
                out[(size_t)row * DIMC + col] = acc[tm][tn][rr] + bias;
            }
    }
}

// ============================ fp32 fallback (round 0) =======================
__global__ __launch_bounds__(192) void k_qkv_attn(
    const float* __restrict__ x, const float* __restrict__ mask,
    const float* __restrict__ qkv_w, const float* __restrict__ qkv_b,
    const float* __restrict__ bias_table, const int* __restrict__ rel_idx,
    float* __restrict__ out)
{
    __shared__ __align__(16) float xs_t[64 * 68];
    __shared__ __align__(16) float qs[NTOK * HD];
    __shared__ __align__(16) float ks_[NTOK * HD];
    __shared__ __align__(16) float vs[NTOK * HD];
    __shared__ __align__(16) union { float w[64 * 96]; float s[NTOK * 56]; } u;

    const int t = threadIdx.x, b = blockIdx.x;
    const int tx = t % 12, ty = t / 12;
    const float* xb = x + (size_t)b * NTOK * DIMC;
    const int mbase = (b % NWIN) * NTOK * NTOK;

    for (int h = 0; h < NHEAD; ++h) {
        float acc[4][8];
        #pragma unroll
        for (int r = 0; r < 4; ++r)
            #pragma unroll
            for (int cc = 0; cc < 8; ++cc) acc[r][cc] = 0.0f;
        for (int c0 = 0; c0 < DIMC; c0 += 64) {
            for (int idx = t; idx < NTOK * 64; idx += 192) {
                int i = idx >> 6, kk2 = idx & 63;
                xs_t[kk2 * 68 + i] = xb[i * DIMC + c0 + kk2];
            }
            for (int idx = t; idx < 64 * 96; idx += 192) {
                int kk2 = idx / 96, c = idx % 96;
                int col = (c >> 5) * DIMC + h * HD + (c & 31);
                u.w[kk2 * 96 + c] = qkv_w[(size_t)(c0 + kk2) * (3 * DIMC) + col];
            }
            __syncthreads();
            #pragma unroll 8
            for (int kk2 = 0; kk2 < 64; ++kk2) {
                const float4 xv = ld4(&xs_t[kk2 * 68 + ty * 4]);
                const float4 w0 = ld4(&u.w[kk2 * 96 + tx * 8]);
                const float4 w1 = ld4(&u.w[kk2 * 96 + tx * 8 + 4]);
                const float xr[4] = {xv.x, xv.y, xv.z, xv.w};
                const float wc[8] = {w0.x, w0.y, w0.z, w0.w, w1.x, w1.y, w1.z, w1.w};
                #pragma unroll
                for (int r = 0; r < 4; ++r)
                    #pragma unroll
                    for (int cc = 0; cc < 8; ++cc)
                        acc[r][cc] = fmaf(xr[r], wc[cc], acc[r][cc]);
            }
            __syncthreads();
        }
        {
            const int part = tx >> 2, cbase = (tx & 3) * 8;
            float* dst = (part == 0) ? qs : (part == 1) ? ks_ : vs;
            #pragma unroll
            for (int r = 0; r < 4; ++r) {
                int i = ty * 4 + r;
                if (i < NTOK)
                    #pragma unroll
                    for (int cc = 0; cc < 8; ++cc) {
                        int c5 = cbase + cc;
                        dst[i * HD + c5] = acc[r][cc] + qkv_b[part * DIMC + h * HD + c5];
                    }
            }
        }
        __syncthreads();
        for (int o = t; o < NTOK * NTOK; o += 192) {
            int i = o / 49, j = o % 49;
            float4 a4 = {0.f, 0.f, 0.f, 0.f};
            #pragma unroll
            for (int seg = 0; seg < 8; ++seg) {
                float4 q4 = ld4(&qs[i * HD + seg * 4]);
                float4 k4 = ld4(&ks_[j * HD + seg * 4]);
                a4.x = fmaf(q4.x, k4.x, a4.x); a4.y = fmaf(q4.y, k4.y, a4.y);
                a4.z = fmaf(q4.z, k4.z, a4.z); a4.w = fmaf(q4.w, k4.w, a4.w);
            }
            u.s[i * 56 + j] = (a4.x + a4.y + a4.z + a4.w) * SCALE
                            + bias_table[rel_idx[o] * NHEAD + h] + mask[mbase + o];
        }
        __syncthreads();
        if (t < NTOK) {
            float* row = &u.s[t * 56];
            float m = row[0];
            for (int j = 1; j < NTOK; ++j) m = fmaxf(m, row[j]);
            float ssum = 0.f;
            for (int j = 0; j < NTOK; ++j) { float e = __expf(row[j] - m); row[j] = e; ssum += e; }
            float inv = 1.0f / ssum;
            for (int j = 0; j < NTOK; ++j) row[j] *= inv;
        }
        __syncthreads();
        for (int o = t; o < NTOK * 8; o += 192) {
            int i = o >> 3, dg = o & 7;
            float4 a = {0.f, 0.f, 0.f, 0.f};
            for (int j = 0; j < NTOK; ++j) {
                float sj = u.s[i * 56 + j];
                float4 v4 = ld4(&vs[j * HD + dg * 4]);
                a.x = fmaf(sj, v4.x, a.x); a.y = fmaf(sj, v4.y, a.y);
                a.z = fmaf(sj, v4.z, a.z); a.w = fmaf(sj, v4.w, a.w);
            }
            *reinterpret_cast<float4*>(&out[(size_t)(b * NTOK + i) * DIMC + h * HD + dg * 4]) = a;
        }
        __syncthreads();
    }
}

__global__ __launch_bounds__(192) void k_proj(
    float* __restrict__ io, const float* __restrict__ proj_w,
    const float* __restrict__ proj_b)
{
    __shared__ __align__(16) float ys_t[DIMC * 20];
    __shared__ __align__(16) float wch[16 * DIMC];
    const int t = threadIdx.x, row0 = blockIdx.x * 16;
    const int tx = t % 48, ty = t / 48;
    for (int idx = t; idx < 16 * DIMC; idx += 192) {
        int i = idx / DIMC, k = idx % DIMC;
        ys_t[k * 20 + i] = io[(size_t)(row0 + i) * DIMC + k];
    }
    float acc[4][8];
    #pragma unroll
    for (int r = 0; r < 4; ++r)
        #pragma unroll
        for (int cc = 0; cc < 8; ++cc) acc[r][cc] = 0.0f;
    for (int k0 = 0; k0 < DIMC; k0 += 16) {
        for (int idx = t; idx < 16 * DIMC; idx += 192) {
            int kk2 = idx / DIMC, c = idx % DIMC;
            wch[kk2 * DIMC + c] = proj_w[(size_t)(k0 + kk2) * DIMC + c];
        }
        __syncthreads();
        #pragma unroll
        for (int kk2 = 0; kk2 < 16; ++kk2) {
            const float4 xv = ld4(&ys_t[(k0 + kk2) * 20 + ty * 4]);
            const float4 w0 = ld4(&wch[kk2 * DIMC + tx * 8]);
            const float4 w1 = ld4(&wch[kk2 * DIMC + tx * 8 + 4]);
            const float xr[4] = {xv.x, xv.y, xv.z, xv.w};
            const float wc[8] = {w0.x, w0.y, w0.z, w0.w, w1.x, w1.y, w1.z, w1.w};
            #pragma unroll
            for (int r = 0; r < 4; ++r)
                #pragma unroll
                for (int cc = 0; cc < 8; ++cc)
                    acc[r][cc] = fmaf(xr[r], wc[cc], acc[r][cc]);
        }
        __syncthreads();
    }
    #pragma unroll
    for (int r = 0; r < 4; ++r) {
        int i = ty * 4 + r;
        float* dst = &io[(size_t)(row0 + i) * DIMC + tx * 8];
        #pragma unroll
        for (int cc = 0; cc < 8; ++cc) dst[cc] = acc[r][cc] + proj_b[tx * 8 + cc];
    }
}

extern "C" void kernel_launch(void* const* d_in, const int* in_sizes, int n_in,
                              void* d_out, int out_size, void* d_ws, size_t ws_size,
                              hipStream_t stream) {
    const float* x          = (const float*)d_in[0];
    const float* mask       = (const float*)d_in[1];
    const float* qkv_w      = (const float*)d_in[2];
    const float* qkv_b      = (const float*)d_in[3];
    const float* proj_w     = (const float*)d_in[4];
    const float* proj_b     = (const float*)d_in[5];
    const float* bias_table = (const float*)d_in[6];
    const int*   rel_idx    = (const int*)d_in[7];
    float* out = (float*)d_out;

    if (ws_size >= WS_NEED) {
        unsigned short* ws = (unsigned short*)d_ws;
        dim3 g1(784, 9);
        k_gemm_qkv<<<g1, 256, 0, stream>>>(x, qkv_w, qkv_b, ws);
        k_attn_scalar<<<BWIN * NHEAD, 256, 0, stream>>>(ws, mask, bias_table, rel_idx);
        dim3 g3(784, 3);
        k_gemm_proj<<<g3, 256, 0, stream>>>(ws, proj_w, proj_b, out);
    } else {
        k_qkv_attn<<<BWIN, 192, 0, stream>>>(x, mask, qkv_w, qkv_b,
                                             bias_table, rel_idx, out);
        k_proj<<<(BWIN * NTOK) / 16, 192, 0, stream>>>(out, proj_w, proj_b);
    }
}